// Round 4
// baseline (231.187 us; speedup 1.0000x reference)
//
#include <hip/hip_runtime.h>

// Problem constants (reference: N=32768, M=8192, D=64, fp32)
#define N_ROWS 32768
#define M_COLS 8192
#define D_DIM  64
#define JC     16                     // j-chunks (grid.y) -> partial mins
#define BLOCK  256
#define ROWS_PER_BLOCK 256            // 4 waves x 64 rows
#define SUBT   ((M_COLS / JC) / 16)   // 32 subtiles of 16 j per chunk

typedef _Float16 v8h __attribute__((ext_vector_type(8)));
typedef _Float16 v4h __attribute__((ext_vector_type(4)));
typedef float    v4f __attribute__((ext_vector_type(4)));

// ---------- kernel 1: yh = (half)y, th[j] = (psi[j] - ||y_j||^2) / 2 ----------
// block handles 16 rows; 16 threads per row, 4 elements each (coalesced).
__global__ __launch_bounds__(BLOCK) void prep_kernel(
    const float* __restrict__ y, const float* __restrict__ psi,
    _Float16* __restrict__ yh, float* __restrict__ th) {
    const int tid = threadIdx.x;
    const int j = blockIdx.x * 16 + (tid >> 4);  // row
    const int n = tid & 15;                      // 4-elem segment
    const float4 v = *(const float4*)(y + (size_t)j * D_DIM + n * 4);
    float s = v.x * v.x + v.y * v.y + v.z * v.z + v.w * v.w;
    v4h hv = { (_Float16)v.x, (_Float16)v.y, (_Float16)v.z, (_Float16)v.w };
    *(v4h*)(yh + (size_t)j * D_DIM + n * 4) = hv;  // 8B store, contiguous
    // reduce sumsq across the 16 lanes of this row (lane bits 0..3)
#pragma unroll
    for (int m = 1; m < 16; m <<= 1) s += __shfl_xor(s, m, 64);
    if (n == 0) th[j] = 0.5f * (psi[j] - s);
}

// ---------- kernel 2: MFMA partial min over a j-chunk ----------
// part[jc*N + i] = min_{j in chunk} (t[j] - 2*<x_i, y_j>)
//               = -2 * max_{j} (<x_i,y_j> + th[j])       (x2 added later)
__global__ __launch_bounds__(BLOCK) void partial_min_kernel(
    const float* __restrict__ x, const _Float16* __restrict__ yh,
    const float* __restrict__ th, float* __restrict__ part) {
    const int tid  = threadIdx.x;
    const int lane = tid & 63, wave = tid >> 6;
    const int q = lane >> 4, n = lane & 15;
    const int jc    = blockIdx.y;
    const int jbase = jc * (M_COLS / JC);
    const int i_wave = blockIdx.x * ROWS_PER_BLOCK + wave * 64;

    // A-frags: 4 row-groups x 2 k-chunks, loaded once from fp32 x, cvt to f16.
    // A layout (16x16x32): m = lane&15, k = quad*8 + idx
    v8h a[4][2];
#pragma unroll
    for (int g = 0; g < 4; ++g) {
        const float* px = x + (size_t)(i_wave + g * 16 + n) * D_DIM + q * 8;
#pragma unroll
        for (int c = 0; c < 2; ++c) {
            float4 f0 = *(const float4*)(px + c * 32);
            float4 f1 = *(const float4*)(px + c * 32 + 4);
            v8h av = { (_Float16)f0.x, (_Float16)f0.y, (_Float16)f0.z, (_Float16)f0.w,
                       (_Float16)f1.x, (_Float16)f1.y, (_Float16)f1.z, (_Float16)f1.w };
            a[g][c] = av;
        }
    }

    float maxs[4][4];
#pragma unroll
    for (int g = 0; g < 4; ++g)
#pragma unroll
        for (int r = 0; r < 4; ++r) maxs[g][r] = -INFINITY;

    // B-frag base: row j = jbase + s*16 + n, k = quad*8 + c*32 (8 halves = 16B)
    const v8h* pb = (const v8h*)yh + ((size_t)(jbase + n) * 8 + q);
    const float* pt = th + jbase + n;

    // software pipeline: prefetch subtile s+1 while computing s
    v8h nb0 = pb[0];
    v8h nb1 = pb[4];
    float ntv = pt[0];

    for (int s = 0; s < SUBT; ++s) {
        const v8h  b0 = nb0;
        const v8h  b1 = nb1;
        const float tv = ntv;
        if (s + 1 < SUBT) {
            nb0 = pb[(size_t)(s + 1) * 128];
            nb1 = pb[(size_t)(s + 1) * 128 + 4];
            ntv = pt[(s + 1) * 16];
        }
#pragma unroll
        for (int g = 0; g < 4; ++g) {
            v4f acc = { tv, tv, tv, tv };  // C-operand carries th[j] for free
            acc = __builtin_amdgcn_mfma_f32_16x16x32_f16(a[g][0], b0, acc, 0, 0, 0);
            acc = __builtin_amdgcn_mfma_f32_16x16x32_f16(a[g][1], b1, acc, 0, 0, 0);
            // C/D: col(j) = lane&15 = n, row(i) = quad*4 + r
#pragma unroll
            for (int r = 0; r < 4; ++r)
                maxs[g][r] = fmaxf(maxs[g][r], acc[r]);
        }
    }

    // reduce max across the 16 j-phase lanes (lane bits 0..3), then store -2*max
#pragma unroll
    for (int g = 0; g < 4; ++g) {
#pragma unroll
        for (int r = 0; r < 4; ++r) {
            float v = maxs[g][r];
#pragma unroll
            for (int m = 1; m < 16; m <<= 1)
                v = fmaxf(v, __shfl_xor(v, m, 64));
            if (n == 0)
                part[(size_t)jc * N_ROWS + i_wave + g * 16 + q * 4 + r] = -2.f * v;
        }
    }
}

// ---------- kernel 3: per-row min over chunks + x2, partial row-sum ----------
__global__ __launch_bounds__(BLOCK) void row_reduce_kernel(
    const float* __restrict__ part, const float* __restrict__ x,
    float* __restrict__ bsum) {
    const int tid = threadIdx.x;
    float s = 0.f;
#pragma unroll
    for (int rr = 0; rr < 2; ++rr) {
        const int i = blockIdx.x * 512 + rr * 256 + tid;
        float m = part[i];
#pragma unroll
        for (int c = 1; c < JC; ++c)
            m = fminf(m, part[(size_t)c * N_ROWS + i]);
        const float4* px = (const float4*)(x + (size_t)i * D_DIM);
        float x2 = 0.f;
#pragma unroll
        for (int k = 0; k < D_DIM / 4; ++k) {
            float4 v = px[k];
            x2 += v.x * v.x + v.y * v.y + v.z * v.z + v.w * v.w;
        }
        s += m + x2;
    }
    for (int off = 32; off > 0; off >>= 1) s += __shfl_down(s, off, 64);
    __shared__ float tmp[4];
    const int lane = tid & 63, wave = tid >> 6;
    if (lane == 0) tmp[wave] = s;
    __syncthreads();
    if (tid == 0) bsum[blockIdx.x] = tmp[0] + tmp[1] + tmp[2] + tmp[3];
}

// ---------- kernel 4: final scalar ----------
__global__ __launch_bounds__(BLOCK) void final_kernel(
    const float* __restrict__ bsum, const float* __restrict__ psi,
    float* __restrict__ out) {
    const int tid = threadIdx.x;
    float s = (tid < 64) ? bsum[tid] : 0.f;
    float p = 0.f;
    for (int j = tid; j < M_COLS; j += BLOCK) p += psi[j];
    for (int off = 32; off > 0; off >>= 1) {
        s += __shfl_down(s, off, 64);
        p += __shfl_down(p, off, 64);
    }
    __shared__ float ts[4], tp[4];
    const int lane = tid & 63, wave = tid >> 6;
    if (lane == 0) { ts[wave] = s; tp[wave] = p; }
    __syncthreads();
    if (tid == 0) {
        float S = ts[0] + ts[1] + ts[2] + ts[3];
        float P = tp[0] + tp[1] + tp[2] + tp[3];
        out[0] = S / (float)N_ROWS + P / (float)M_COLS;
    }
}

extern "C" void kernel_launch(void* const* d_in, const int* in_sizes, int n_in,
                              void* d_out, int out_size, void* d_ws, size_t ws_size,
                              hipStream_t stream) {
    const float* x   = (const float*)d_in[0];   // [N,D]
    const float* y   = (const float*)d_in[1];   // [M,D]
    const float* psi = (const float*)d_in[2];   // [M]
    float* out = (float*)d_out;

    // workspace layout
    float* part = (float*)d_ws;                       // JC*N floats = 2 MB
    float* th   = part + (size_t)JC * N_ROWS;         // M floats
    float* bsum = th + M_COLS;                        // 64 floats
    _Float16* yh = (_Float16*)(bsum + 64);            // M*D halves = 1 MB (16B-aligned)

    prep_kernel<<<M_COLS / 16, BLOCK, 0, stream>>>(y, psi, yh, th);
    partial_min_kernel<<<dim3(N_ROWS / ROWS_PER_BLOCK, JC), BLOCK, 0, stream>>>(x, yh, th, part);
    row_reduce_kernel<<<N_ROWS / 512, BLOCK, 0, stream>>>(part, x, bsum);
    final_kernel<<<1, BLOCK, 0, stream>>>(bsum, psi, out);
}

// Round 5
// 155.675 us; speedup vs baseline: 1.4851x; 1.4851x over previous
//
#include <hip/hip_runtime.h>

// Problem constants (reference: N=32768, M=8192, D=64, fp32)
#define N_ROWS 32768
#define M_COLS 8192
#define D_DIM  64
#define JC     16                     // j-chunks (grid.y) -> partial mins
#define BLOCK  256
#define ROWS_PER_BLOCK 256            // 4 waves x 64 rows
#define SUBT   ((M_COLS / JC) / 16)   // 32 subtiles of 16 j per chunk

typedef _Float16 v8h __attribute__((ext_vector_type(8)));
typedef _Float16 v4h __attribute__((ext_vector_type(4)));
typedef float    v4f __attribute__((ext_vector_type(4)));

// ---------- kernel 1: yh = (half)y, th[j] = (psi[j] - ||y_j||^2) / 2 ----------
__global__ __launch_bounds__(BLOCK) void prep_kernel(
    const float* __restrict__ y, const float* __restrict__ psi,
    _Float16* __restrict__ yh, float* __restrict__ th) {
    const int tid = threadIdx.x;
    const int j = blockIdx.x * 16 + (tid >> 4);  // row
    const int n = tid & 15;                      // 4-elem segment
    const float4 v = *(const float4*)(y + (size_t)j * D_DIM + n * 4);
    float s = v.x * v.x + v.y * v.y + v.z * v.z + v.w * v.w;
    v4h hv = { (_Float16)v.x, (_Float16)v.y, (_Float16)v.z, (_Float16)v.w };
    *(v4h*)(yh + (size_t)j * D_DIM + n * 4) = hv;  // 8B store, contiguous
#pragma unroll
    for (int m = 1; m < 16; m <<= 1) s += __shfl_xor(s, m, 64);
    if (n == 0) th[j] = 0.5f * (psi[j] - s);
}

// ---------- kernel 2: MFMA partial min over a j-chunk ----------
// part[jc*N + i] = min_{j in chunk} (t[j] - 2*<x_i,y_j>)
//               = -2 * max_{j} (<x_i,y_j> + th[j])       (x2 added later)
__global__ __launch_bounds__(BLOCK) void partial_min_kernel(
    const float* __restrict__ x, const _Float16* __restrict__ yh,
    const float* __restrict__ th, float* __restrict__ part) {
    const int tid  = threadIdx.x;
    const int lane = tid & 63, wave = tid >> 6;
    const int q = lane >> 4, n = lane & 15;
    const int jc    = blockIdx.y;
    const int jbase = jc * (M_COLS / JC);
    const int i_wave = blockIdx.x * ROWS_PER_BLOCK + wave * 64;

    // A-frags: 4 row-groups x 2 k-chunks, loaded once from fp32 x, cvt to f16.
    // A layout (16x16x32): m = lane&15, k = quad*8 + idx
    v8h a[4][2];
#pragma unroll
    for (int g = 0; g < 4; ++g) {
        const float* px = x + (size_t)(i_wave + g * 16 + n) * D_DIM + q * 8;
#pragma unroll
        for (int c = 0; c < 2; ++c) {
            float4 f0 = *(const float4*)(px + c * 32);
            float4 f1 = *(const float4*)(px + c * 32 + 4);
            v8h av = { (_Float16)f0.x, (_Float16)f0.y, (_Float16)f0.z, (_Float16)f0.w,
                       (_Float16)f1.x, (_Float16)f1.y, (_Float16)f1.z, (_Float16)f1.w };
            a[g][c] = av;
        }
    }

    float maxs[4][4];
#pragma unroll
    for (int g = 0; g < 4; ++g)
#pragma unroll
        for (int r = 0; r < 4; ++r) maxs[g][r] = -INFINITY;

    // B-frag base: row j = jbase + s*16 + n, k = quad*8 + c*32 (8 halves = 16B)
    const v8h* pb = (const v8h*)yh + ((size_t)(jbase + n) * 8 + q);
    const float* pt = th + jbase + n;

#pragma unroll 2
    for (int s = 0; s < SUBT; ++s) {
        const v8h b0 = pb[(size_t)s * 128];      // c=0
        const v8h b1 = pb[(size_t)s * 128 + 4];  // c=1 (+32 halves)
        const float tv = pt[s * 16];
        const v4f tv4 = { tv, tv, tv, tv };      // th[j] rides in the C operand
#pragma unroll
        for (int g = 0; g < 4; ++g) {
            v4f acc = __builtin_amdgcn_mfma_f32_16x16x32_f16(a[g][0], b0, tv4, 0, 0, 0);
            acc     = __builtin_amdgcn_mfma_f32_16x16x32_f16(a[g][1], b1, acc, 0, 0, 0);
            // C/D: col(j) = lane&15 = n, row(i) = quad*4 + r
#pragma unroll
            for (int r = 0; r < 4; ++r)
                maxs[g][r] = fmaxf(maxs[g][r], acc[r]);
        }
    }

    // reduce max across the 16 j-phase lanes (lane bits 0..3), store -2*max
#pragma unroll
    for (int g = 0; g < 4; ++g) {
#pragma unroll
        for (int r = 0; r < 4; ++r) {
            float v = maxs[g][r];
#pragma unroll
            for (int m = 1; m < 16; m <<= 1)
                v = fmaxf(v, __shfl_xor(v, m, 64));
            if (n == 0)
                part[(size_t)jc * N_ROWS + i_wave + g * 16 + q * 4 + r] = -2.f * v;
        }
    }
}

// ---------- kernel 3: per-row min over chunks + x2, partial row-sum ----------
__global__ __launch_bounds__(BLOCK) void row_reduce_kernel(
    const float* __restrict__ part, const float* __restrict__ x,
    float* __restrict__ bsum) {
    const int tid = threadIdx.x;
    float s = 0.f;
#pragma unroll
    for (int rr = 0; rr < 2; ++rr) {
        const int i = blockIdx.x * 512 + rr * 256 + tid;
        float m = part[i];
#pragma unroll
        for (int c = 1; c < JC; ++c)
            m = fminf(m, part[(size_t)c * N_ROWS + i]);
        const float4* px = (const float4*)(x + (size_t)i * D_DIM);
        float x2 = 0.f;
#pragma unroll
        for (int k = 0; k < D_DIM / 4; ++k) {
            float4 v = px[k];
            x2 += v.x * v.x + v.y * v.y + v.z * v.z + v.w * v.w;
        }
        s += m + x2;
    }
    for (int off = 32; off > 0; off >>= 1) s += __shfl_down(s, off, 64);
    __shared__ float tmp[4];
    const int lane = tid & 63, wave = tid >> 6;
    if (lane == 0) tmp[wave] = s;
    __syncthreads();
    if (tid == 0) bsum[blockIdx.x] = tmp[0] + tmp[1] + tmp[2] + tmp[3];
}

// ---------- kernel 4: final scalar ----------
__global__ __launch_bounds__(BLOCK) void final_kernel(
    const float* __restrict__ bsum, const float* __restrict__ psi,
    float* __restrict__ out) {
    const int tid = threadIdx.x;
    float s = (tid < 64) ? bsum[tid] : 0.f;
    float p = 0.f;
    for (int j = tid; j < M_COLS; j += BLOCK) p += psi[j];
    for (int off = 32; off > 0; off >>= 1) {
        s += __shfl_down(s, off, 64);
        p += __shfl_down(p, off, 64);
    }
    __shared__ float ts[4], tp[4];
    const int lane = tid & 63, wave = tid >> 6;
    if (lane == 0) { ts[wave] = s; tp[wave] = p; }
    __syncthreads();
    if (tid == 0) {
        float S = ts[0] + ts[1] + ts[2] + ts[3];
        float P = tp[0] + tp[1] + tp[2] + tp[3];
        out[0] = S / (float)N_ROWS + P / (float)M_COLS;
    }
}

extern "C" void kernel_launch(void* const* d_in, const int* in_sizes, int n_in,
                              void* d_out, int out_size, void* d_ws, size_t ws_size,
                              hipStream_t stream) {
    const float* x   = (const float*)d_in[0];   // [N,D]
    const float* y   = (const float*)d_in[1];   // [M,D]
    const float* psi = (const float*)d_in[2];   // [M]
    float* out = (float*)d_out;

    // workspace layout
    float* part = (float*)d_ws;                       // JC*N floats = 2 MB
    float* th   = part + (size_t)JC * N_ROWS;         // M floats
    float* bsum = th + M_COLS;                        // 64 floats
    _Float16* yh = (_Float16*)(bsum + 64);            // M*D halves = 1 MB (16B-aligned)

    prep_kernel<<<M_COLS / 16, BLOCK, 0, stream>>>(y, psi, yh, th);
    partial_min_kernel<<<dim3(N_ROWS / ROWS_PER_BLOCK, JC), BLOCK, 0, stream>>>(x, yh, th, part);
    row_reduce_kernel<<<N_ROWS / 512, BLOCK, 0, stream>>>(part, x, bsum);
    final_kernel<<<1, BLOCK, 0, stream>>>(bsum, psi, out);
}

// Round 6
// 121.932 us; speedup vs baseline: 1.8960x; 1.2767x over previous
//
#include <hip/hip_runtime.h>

// Problem constants (reference: N=32768, M=8192, D=64, fp32)
#define N_ROWS 32768
#define M_COLS 8192
#define D_DIM  64
#define JC     8                      // j-chunks (grid.y) -> partial mins
#define BLOCK  256
#define ROWS_PER_BLOCK 256            // 4 waves x 64 rows
#define CHUNK  (M_COLS / JC)          // 1024 j per chunk
#define TJ     128                    // j per LDS tile (128 rows x 128 B = 16 KB)
#define NTILE  (CHUNK / TJ)           // 8 tiles per chunk

typedef _Float16 v8h __attribute__((ext_vector_type(8)));
typedef _Float16 v4h __attribute__((ext_vector_type(4)));
typedef float    v4f __attribute__((ext_vector_type(4)));

// ---------- kernel 1: yh = (half)y, th[j] = (psi[j] - ||y_j||^2) / 2 ----------
__global__ __launch_bounds__(BLOCK) void prep_kernel(
    const float* __restrict__ y, const float* __restrict__ psi,
    _Float16* __restrict__ yh, float* __restrict__ th) {
    const int tid = threadIdx.x;
    const int j = blockIdx.x * 16 + (tid >> 4);  // row
    const int n = tid & 15;                      // 4-elem segment
    const float4 v = *(const float4*)(y + (size_t)j * D_DIM + n * 4);
    float s = v.x * v.x + v.y * v.y + v.z * v.z + v.w * v.w;
    v4h hv = { (_Float16)v.x, (_Float16)v.y, (_Float16)v.z, (_Float16)v.w };
    *(v4h*)(yh + (size_t)j * D_DIM + n * 4) = hv;
#pragma unroll
    for (int m = 1; m < 16; m <<= 1) s += __shfl_xor(s, m, 64);
    if (n == 0) th[j] = 0.5f * (psi[j] - s);
}

// ---------- kernel 2: MFMA partial min over a j-chunk ----------
// part[jc*N + i] = min_{j in chunk} (t[j] - 2<x_i,y_j>) = -2 max_j(<x_i,y_j>+th[j])
// B staged global->LDS (async, double-buffered, XOR-swizzled), A in registers.
__global__ __launch_bounds__(BLOCK) void partial_min_kernel(
    const float* __restrict__ x, const _Float16* __restrict__ yh,
    const float* __restrict__ th, float* __restrict__ part) {
    __shared__ __align__(16) _Float16 sY[2][TJ * D_DIM];  // 2 x 16 KB

    const int tid  = threadIdx.x;
    const int lane = tid & 63, wave = tid >> 6;
    const int q = lane >> 4, n = lane & 15;
    const int jc    = blockIdx.y;
    const int jbase = jc * CHUNK;
    const int i_wave = blockIdx.x * ROWS_PER_BLOCK + wave * 64;

    // A-frags: 4 row-groups x 2 k-chunks, loaded once from fp32 x, cvt to f16.
    v8h a[4][2];
#pragma unroll
    for (int g = 0; g < 4; ++g) {
        const float* px = x + (size_t)(i_wave + g * 16 + n) * D_DIM + q * 8;
#pragma unroll
        for (int c = 0; c < 2; ++c) {
            float4 f0 = *(const float4*)(px + c * 32);
            float4 f1 = *(const float4*)(px + c * 32 + 4);
            v8h av = { (_Float16)f0.x, (_Float16)f0.y, (_Float16)f0.z, (_Float16)f0.w,
                       (_Float16)f1.x, (_Float16)f1.y, (_Float16)f1.z, (_Float16)f1.w };
            a[g][c] = av;
        }
    }

    float maxs[4][4];
#pragma unroll
    for (int g = 0; g < 4; ++g)
#pragma unroll
        for (int r = 0; r < 4; ++r) maxs[g][r] = -INFINITY;

    // ---- async stage of tile t into buffer b (swizzled on the GLOBAL side) ----
    // LDS slot sIdx (16B units) holds (row = sIdx/8, chunk = (sIdx%8) ^ (row&7)).
    // 4 rounds x (4 waves x 64 lanes x 16B) = 16 KB.
    auto stage = [&](int t, int b) {
#pragma unroll
        for (int k = 0; k < 4; ++k) {
            const int sIdx = (k * 4 + wave) * 64 + lane;     // [0,1024)
            const int row  = sIdx >> 3;
            const int c    = (sIdx & 7) ^ (row & 7);
            const _Float16* g = yh + (size_t)(jbase + t * TJ + row) * D_DIM + c * 8;
            __builtin_amdgcn_global_load_lds(
                (const __attribute__((address_space(1))) void*)g,
                (__attribute__((address_space(3))) void*)(&sY[b][(size_t)(k * 4 + wave) * 512]),
                16, 0, 0);
        }
    };

    stage(0, 0);
    __syncthreads();  // drains vmcnt(0): tile 0 resident

    const int sl0 = q ^ (n & 7);  // swizzled slot for chunk q of row (..8k+n)

    for (int t = 0; t < NTILE; ++t) {
        const int cur = t & 1;
        if (t + 1 < NTILE) stage(t + 1, cur ^ 1);  // prefetch under compute

        const _Float16* buf = &sY[cur][0];
        const float* pt = th + jbase + t * TJ + n;
#pragma unroll 2
        for (int ss = 0; ss < TJ / 16; ++ss) {
            // row in tile = ss*16+n (row&7 == n&7); chunk q at slot sl0, q+4 at sl0^4
            const v8h b0 = *(const v8h*)(buf + (ss * 16 + n) * 64 + sl0 * 8);
            const v8h b1 = *(const v8h*)(buf + (ss * 16 + n) * 64 + (sl0 ^ 4) * 8);
            const float tv = pt[ss * 16];
            const v4f tv4 = { tv, tv, tv, tv };   // th[j] rides in the C operand
#pragma unroll
            for (int g = 0; g < 4; ++g) {
                v4f acc = __builtin_amdgcn_mfma_f32_16x16x32_f16(a[g][0], b0, tv4, 0, 0, 0);
                acc     = __builtin_amdgcn_mfma_f32_16x16x32_f16(a[g][1], b1, acc, 0, 0, 0);
#pragma unroll
                for (int r = 0; r < 4; ++r)
                    maxs[g][r] = fmaxf(maxs[g][r], acc[r]);
            }
        }
        __syncthreads();  // all waves done reading buf `cur`; prefetch drained
    }

    // reduce max across the 16 j-phase lanes (lane bits 0..3), store -2*max
#pragma unroll
    for (int g = 0; g < 4; ++g) {
#pragma unroll
        for (int r = 0; r < 4; ++r) {
            float v = maxs[g][r];
#pragma unroll
            for (int m = 1; m < 16; m <<= 1)
                v = fmaxf(v, __shfl_xor(v, m, 64));
            if (n == 0)
                part[(size_t)jc * N_ROWS + i_wave + g * 16 + q * 4 + r] = -2.f * v;
        }
    }
}

// ---------- kernel 3: fused reduce ----------
// out += [ sum_i min_c part[c][i] + sum(x^2) ] / N + sum(psi) / M
// (mean_i x2_i separates from the min, so x^2 needs no row alignment)
__global__ __launch_bounds__(BLOCK) void reduce_kernel(
    const float* __restrict__ part, const float* __restrict__ x,
    const float* __restrict__ psi, float* __restrict__ out) {
    const int tid = threadIdx.x;
    const int gt  = blockIdx.x * BLOCK + tid;     // [0, 32768)
    float m = part[gt];
#pragma unroll
    for (int c = 1; c < JC; ++c)
        m = fminf(m, part[(size_t)c * N_ROWS + gt]);
    float s = m;
    const float4* xv = (const float4*)x;          // N*D/4 = 524288 float4
    float x2 = 0.f;
#pragma unroll
    for (int k = 0; k < 16; ++k) {
        float4 v = xv[gt + k * 32768];
        x2 += v.x * v.x + v.y * v.y + v.z * v.z + v.w * v.w;
    }
    s = (s + x2) * (1.f / (float)N_ROWS);
    if (gt < M_COLS) s += psi[gt] * (1.f / (float)M_COLS);
    for (int off = 32; off > 0; off >>= 1) s += __shfl_down(s, off, 64);
    __shared__ float tmp[4];
    if ((tid & 63) == 0) tmp[tid >> 6] = s;
    __syncthreads();
    if (tid == 0) atomicAdd(out, tmp[0] + tmp[1] + tmp[2] + tmp[3]);
}

extern "C" void kernel_launch(void* const* d_in, const int* in_sizes, int n_in,
                              void* d_out, int out_size, void* d_ws, size_t ws_size,
                              hipStream_t stream) {
    const float* x   = (const float*)d_in[0];   // [N,D]
    const float* y   = (const float*)d_in[1];   // [M,D]
    const float* psi = (const float*)d_in[2];   // [M]
    float* out = (float*)d_out;

    // workspace layout
    float* part = (float*)d_ws;                       // JC*N floats = 1 MB
    float* th   = part + (size_t)JC * N_ROWS;         // M floats
    _Float16* yh = (_Float16*)(th + M_COLS);          // M*D halves = 1 MB (16B-aligned)

    hipMemsetAsync(out, 0, sizeof(float), stream);    // atomic accumulator
    prep_kernel<<<M_COLS / 16, BLOCK, 0, stream>>>(y, psi, yh, th);
    partial_min_kernel<<<dim3(N_ROWS / ROWS_PER_BLOCK, JC), BLOCK, 0, stream>>>(x, yh, th, part);
    reduce_kernel<<<N_ROWS / BLOCK, BLOCK, 0, stream>>>(part, x, psi, out);
}

// Round 7
// 106.215 us; speedup vs baseline: 2.1766x; 1.1480x over previous
//
#include <hip/hip_runtime.h>

// Problem constants (reference: N=32768, M=8192, D=64, fp32)
#define N_ROWS 32768
#define M_COLS 8192
#define D_DIM  64
#define JC     8                      // j-chunks (grid.y) -> partial mins
#define BLOCK  256
#define GROUPS 8                      // 16-row groups per wave -> 128 rows/wave
#define ROWS_PER_BLOCK 512            // 4 waves x 128 rows
#define CHUNK  (M_COLS / JC)          // 1024 j per chunk
#define TJ     128                    // j per LDS tile (128 rows x 128 B = 16 KB)
#define NTILE  (CHUNK / TJ)           // 8 tiles per chunk

typedef _Float16 v8h __attribute__((ext_vector_type(8)));
typedef _Float16 v4h __attribute__((ext_vector_type(4)));
typedef float    v4f __attribute__((ext_vector_type(4)));

// ---------- kernel 1: yh = (half)y, th[j] = (psi[j] - ||y_j||^2)/2; zero out ----------
__global__ __launch_bounds__(BLOCK) void prep_kernel(
    const float* __restrict__ y, const float* __restrict__ psi,
    _Float16* __restrict__ yh, float* __restrict__ th, float* __restrict__ out) {
    const int tid = threadIdx.x;
    if (blockIdx.x == 0 && tid == 0) out[0] = 0.f;   // atomic accumulator init
    const int j = blockIdx.x * 16 + (tid >> 4);  // row
    const int n = tid & 15;                      // 4-elem segment
    const float4 v = *(const float4*)(y + (size_t)j * D_DIM + n * 4);
    float s = v.x * v.x + v.y * v.y + v.z * v.z + v.w * v.w;
    v4h hv = { (_Float16)v.x, (_Float16)v.y, (_Float16)v.z, (_Float16)v.w };
    *(v4h*)(yh + (size_t)j * D_DIM + n * 4) = hv;
#pragma unroll
    for (int m = 1; m < 16; m <<= 1) s += __shfl_xor(s, m, 64);
    if (n == 0) th[j] = 0.5f * (psi[j] - s);
}

// ---------- kernel 2: MFMA partial min over a j-chunk ----------
// part[jc*N + i] = min_{j in chunk} (t[j] - 2<x_i,y_j>) = -2 max_j(<x_i,y_j>+th[j])
// B + th staged global->LDS (async, double-buffered, XOR-swizzled); A in regs.
// 8 row-groups/wave: 16 MFMAs per (B-frag pair + tv) -> MFMA-pipe-bound by ILP.
__global__ __launch_bounds__(BLOCK) void partial_min_kernel(
    const float* __restrict__ x, const _Float16* __restrict__ yh,
    const float* __restrict__ th, float* __restrict__ part) {
    __shared__ __align__(16) _Float16 sY[2][TJ * D_DIM];  // 2 x 16 KB
    __shared__ __align__(16) float    sTh[2][TJ];         // 2 x 512 B

    const int tid  = threadIdx.x;
    const int lane = tid & 63, wave = tid >> 6;
    const int q = lane >> 4, n = lane & 15;
    const int jc    = blockIdx.y;
    const int jbase = jc * CHUNK;
    const int i_wave = blockIdx.x * ROWS_PER_BLOCK + wave * 128;

    // A-frags: 8 row-groups x 2 k-chunks, loaded once from fp32 x, cvt to f16.
    v8h a[GROUPS][2];
#pragma unroll
    for (int g = 0; g < GROUPS; ++g) {
        const float* px = x + (size_t)(i_wave + g * 16 + n) * D_DIM + q * 8;
#pragma unroll
        for (int c = 0; c < 2; ++c) {
            float4 f0 = *(const float4*)(px + c * 32);
            float4 f1 = *(const float4*)(px + c * 32 + 4);
            v8h av = { (_Float16)f0.x, (_Float16)f0.y, (_Float16)f0.z, (_Float16)f0.w,
                       (_Float16)f1.x, (_Float16)f1.y, (_Float16)f1.z, (_Float16)f1.w };
            a[g][c] = av;
        }
    }

    float maxs[GROUPS][4];
#pragma unroll
    for (int g = 0; g < GROUPS; ++g)
#pragma unroll
        for (int r = 0; r < 4; ++r) maxs[g][r] = -INFINITY;

    // ---- async stage of tile t into buffer b (swizzled on the GLOBAL side) ----
    // LDS slot sIdx (16B units) holds (row = sIdx/8, chunk = (sIdx%8) ^ (row&7)).
    auto stage = [&](int t, int b) {
#pragma unroll
        for (int k = 0; k < 4; ++k) {
            const int sIdx = (k * 4 + wave) * 64 + lane;     // [0,1024)
            const int row  = sIdx >> 3;
            const int c    = (sIdx & 7) ^ (row & 7);
            const _Float16* g = yh + (size_t)(jbase + t * TJ + row) * D_DIM + c * 8;
            __builtin_amdgcn_global_load_lds(
                (const __attribute__((address_space(1))) void*)g,
                (__attribute__((address_space(3))) void*)(&sY[b][(size_t)(k * 4 + wave) * 512]),
                16, 0, 0);
        }
        // th tile: 128 floats = 512 B via wave 0, lanes 0-31 (lane*16B dest)
        if (wave == 0 && lane < 32) {
            const float* gt_ = th + jbase + t * TJ + lane * 4;
            __builtin_amdgcn_global_load_lds(
                (const __attribute__((address_space(1))) void*)gt_,
                (__attribute__((address_space(3))) void*)(&sTh[b][0]),
                16, 0, 0);
        }
    };

    stage(0, 0);
    __syncthreads();  // drains vmcnt(0): tile 0 resident

    const int sl0 = q ^ (n & 7);  // swizzled slot for chunk q of row (..8k+n)

    for (int t = 0; t < NTILE; ++t) {
        const int cur = t & 1;
        if (t + 1 < NTILE) stage(t + 1, cur ^ 1);  // prefetch under compute

        const _Float16* buf = &sY[cur][0];
        const float* tbuf = &sTh[cur][0];
#pragma unroll 4
        for (int ss = 0; ss < TJ / 16; ++ss) {
            // row in tile = ss*16+n (row&7 == n&7); chunk q at slot sl0, q+4 at sl0^4
            const v8h b0 = *(const v8h*)(buf + (ss * 16 + n) * 64 + sl0 * 8);
            const v8h b1 = *(const v8h*)(buf + (ss * 16 + n) * 64 + (sl0 ^ 4) * 8);
            const float tv = tbuf[ss * 16 + n];
            const v4f tv4 = { tv, tv, tv, tv };   // th[j] rides in the C operand
#pragma unroll
            for (int g = 0; g < GROUPS; ++g) {
                v4f acc = __builtin_amdgcn_mfma_f32_16x16x32_f16(a[g][0], b0, tv4, 0, 0, 0);
                acc     = __builtin_amdgcn_mfma_f32_16x16x32_f16(a[g][1], b1, acc, 0, 0, 0);
#pragma unroll
                for (int r = 0; r < 4; ++r)
                    maxs[g][r] = fmaxf(maxs[g][r], acc[r]);
            }
        }
        __syncthreads();  // all waves done reading buf `cur`; prefetch drained
    }

    // reduce max across the 16 j-phase lanes (lane bits 0..3), store -2*max
#pragma unroll
    for (int g = 0; g < GROUPS; ++g) {
#pragma unroll
        for (int r = 0; r < 4; ++r) {
            float v = maxs[g][r];
#pragma unroll
            for (int m = 1; m < 16; m <<= 1)
                v = fmaxf(v, __shfl_xor(v, m, 64));
            if (n == 0)
                part[(size_t)jc * N_ROWS + i_wave + g * 16 + q * 4 + r] = -2.f * v;
        }
    }
}

// ---------- kernel 3: fused reduce ----------
// out += [ sum_i min_c part[c][i] + sum(x^2) ] / N + sum(psi) / M
__global__ __launch_bounds__(BLOCK) void reduce_kernel(
    const float* __restrict__ part, const float* __restrict__ x,
    const float* __restrict__ psi, float* __restrict__ out) {
    const int tid = threadIdx.x;
    const int gt  = blockIdx.x * BLOCK + tid;     // [0, 32768)
    float m = part[gt];
#pragma unroll
    for (int c = 1; c < JC; ++c)
        m = fminf(m, part[(size_t)c * N_ROWS + gt]);
    float s = m;
    const float4* xv = (const float4*)x;          // N*D/4 = 524288 float4
    float x2 = 0.f;
#pragma unroll
    for (int k = 0; k < 16; ++k) {
        float4 v = xv[gt + k * 32768];
        x2 += v.x * v.x + v.y * v.y + v.z * v.z + v.w * v.w;
    }
    s = (s + x2) * (1.f / (float)N_ROWS);
    if (gt < M_COLS) s += psi[gt] * (1.f / (float)M_COLS);
    for (int off = 32; off > 0; off >>= 1) s += __shfl_down(s, off, 64);
    __shared__ float tmp[4];
    if ((tid & 63) == 0) tmp[tid >> 6] = s;
    __syncthreads();
    if (tid == 0) atomicAdd(out, tmp[0] + tmp[1] + tmp[2] + tmp[3]);
}

extern "C" void kernel_launch(void* const* d_in, const int* in_sizes, int n_in,
                              void* d_out, int out_size, void* d_ws, size_t ws_size,
                              hipStream_t stream) {
    const float* x   = (const float*)d_in[0];   // [N,D]
    const float* y   = (const float*)d_in[1];   // [M,D]
    const float* psi = (const float*)d_in[2];   // [M]
    float* out = (float*)d_out;

    // workspace layout
    float* part = (float*)d_ws;                       // JC*N floats = 1 MB
    float* th   = part + (size_t)JC * N_ROWS;         // M floats
    _Float16* yh = (_Float16*)(th + M_COLS);          // M*D halves = 1 MB (16B-aligned)

    prep_kernel<<<M_COLS / 16, BLOCK, 0, stream>>>(y, psi, yh, th, out);
    partial_min_kernel<<<dim3(N_ROWS / ROWS_PER_BLOCK, JC), BLOCK, 0, stream>>>(x, yh, th, part);
    reduce_kernel<<<N_ROWS / BLOCK, BLOCK, 0, stream>>>(part, x, psi, out);
}